// Round 3
// baseline (217.576 us; speedup 1.0000x reference)
//
#include <hip/hip_runtime.h>
#include <math.h>

#define NPROP 2000
#define NCLS  81
#define NFG   80
#define NDET  100
#define NBLK  256
#define VMAX  512
#define WMAX  16          // VMAX/32 words per suppression-matrix row

#define IMGW 800.0f
#define IMGH 800.0f
#define SCORE_THRESH 0.05f
#define NMS_THRESH 0.5f
#define MIN_SIZE 1.0f
#define BBOX_CLIP 4.135166556742356f  // log(1000/16)

// single kernel: one block per foreground class; softmax stats computed in-block
__global__ __launch_bounds__(NBLK) void perclass_kernel(
        const float* __restrict__ logits,  // [NPROP, NCLS]
        const float* __restrict__ reg,     // [NPROP, NCLS*4]
        const float* __restrict__ prop,    // [NPROP, 4]
        float* __restrict__ out) {
    const int c    = blockIdx.x + 1;   // foreground class 1..80
    const int tid  = threadIdx.x;
    const int lane = tid & 63;
    const int wv   = tid >> 6;

    __shared__ float s_x1u[NPROP], s_y1u[NPROP], s_x2u[NPROP], s_y2u[NPROP];
    __shared__ float s_scu[NPROP];                 // score if valid else -1
    __shared__ float s_vsc[NPROP];                 // valid-list scores (unordered)
    __shared__ unsigned short s_vlist[NPROP];      // valid-list original indices
    __shared__ unsigned short s_ord[NPROP];        // rank -> original index
    __shared__ unsigned char  s_keep[NPROP];       // fallback path only
    __shared__ unsigned int   s_supm[VMAX * WMAX]; // suppression bit matrix
    __shared__ unsigned short s_keepOut[NDET], s_supOut[NDET], s_invOut[NDET];
    __shared__ int s_cnt, s_K, s_wcnt[4];

    if (tid == 0) s_cnt = 0;
    __syncthreads();

    // ---- phase 1: softmax stats (sequential order!) + decode + clip + valid ----
    for (int n = tid; n < NPROP; n += NBLK) {
        const float* row = logits + n * NCLS;
        float m = -1e30f;
        for (int k = 0; k < NCLS; ++k) m = fmaxf(m, row[k]);
        float sm = 0.0f;
        for (int k = 0; k < NCLS; ++k) sm += expf(row[k] - m);
        float lg = row[c];
        float sc = expf(lg - m) / sm;

        float4 pr = ((const float4*)prop)[n];
        float w  = pr.z - pr.x, h = pr.w - pr.y;
        float cx = pr.x + 0.5f * w, cy = pr.y + 0.5f * h;
        float4 d = *(const float4*)(reg + (size_t)n * (NCLS * 4) + c * 4);
        float dx = d.x / 10.0f;
        float dy = d.y / 10.0f;
        float dw = fminf(d.z / 5.0f, BBOX_CLIP);
        float dh = fminf(d.w / 5.0f, BBOX_CLIP);
        float pcx = dx * w + cx;
        float pcy = dy * h + cy;
        float pw  = expf(dw) * w;
        float ph  = expf(dh) * h;
        float bx1 = fminf(fmaxf(pcx - 0.5f * pw, 0.0f), IMGW);
        float by1 = fminf(fmaxf(pcy - 0.5f * ph, 0.0f), IMGH);
        float bx2 = fminf(fmaxf(pcx + 0.5f * pw, 0.0f), IMGW);
        float by2 = fminf(fmaxf(pcy + 0.5f * ph, 0.0f), IMGH);
        s_x1u[n] = bx1; s_y1u[n] = by1; s_x2u[n] = bx2; s_y2u[n] = by2;
        bool valid = (sc >= SCORE_THRESH) && ((bx2 - bx1) >= MIN_SIZE)
                                          && ((by2 - by1) >= MIN_SIZE);
        s_scu[n] = valid ? sc : -1.0f;
        if (valid) {
            int p = atomicAdd(&s_cnt, 1);
            s_vlist[p] = (unsigned short)n;
            s_vsc[p]   = sc;
        }
    }
    __syncthreads();
    const int V = s_cnt;

    // ---- phase 2: rank sort (score desc, index asc) ----
    for (int i = tid; i < V; i += NBLK) {
        float si = s_vsc[i];
        int   ni = s_vlist[i];
        int r = 0;
        for (int j = 0; j < V; ++j) {
            float sj = s_vsc[j];
            int   nj = s_vlist[j];
            r += (sj > si) || (sj == si && nj < ni);
        }
        s_ord[r] = (unsigned short)ni;
    }
    __syncthreads();

    int K;

    if (V <= VMAX) {
        // ---- phase 3a: build suppression bit matrix in parallel ----
        const int W = (V + 31) >> 5;
        for (int t = tid; t < V * W; t += NBLK) {
            int i = t / W, w = t - i * W;
            int ni = s_ord[i];
            float ax1 = s_x1u[ni], ay1 = s_y1u[ni], ax2 = s_x2u[ni], ay2 = s_y2u[ni];
            float areaA = (ax2 - ax1) * (ay2 - ay1);
            unsigned int bits = 0;
            int jbase = w << 5;
            int jend  = (jbase + 32 < V) ? jbase + 32 : V;
            int j0    = (jbase > i + 1) ? jbase : i + 1;
            for (int j = j0; j < jend; ++j) {
                int nj = s_ord[j];
                float bx1 = s_x1u[nj], by1 = s_y1u[nj], bx2 = s_x2u[nj], by2 = s_y2u[nj];
                float areaB = (bx2 - bx1) * (by2 - by1);
                float lx = fmaxf(ax1, bx1), ly = fmaxf(ay1, by1);
                float rx = fminf(ax2, bx2), ry = fminf(ay2, by2);
                float iw = fmaxf(rx - lx, 0.0f), ih = fmaxf(ry - ly, 0.0f);
                float inter = iw * ih;
                float iou = inter / (areaA + areaB - inter + 1e-9f);
                if (iou > NMS_THRESH) bits |= 1u << (j - jbase);
            }
            s_supm[i * W + w] = bits;
        }
        __syncthreads();

        // ---- phase 4a: serial greedy scan, single wave, register keep-mask ----
        unsigned int kw = 0;                    // lane l owns keep word l
        if (wv == 0) {
            int base = lane << 5;
            if (base < V) kw = (V - base >= 32) ? 0xffffffffu
                                                : ((1u << (V - base)) - 1u);
            int nk = 0;
            unsigned int nrow = (V > 0 && lane < W) ? s_supm[lane] : 0u;
            for (int i = 0; i < V; ++i) {
                unsigned int rowb = nrow;
                if (i + 1 < V) nrow = (lane < W) ? s_supm[(i + 1) * W + lane] : 0u;
                unsigned int kword = (unsigned int)__shfl((int)kw, i >> 5);
                if ((kword >> (i & 31)) & 1u) {
                    if (lane == 0) s_keepOut[nk] = (unsigned short)i;
                    ++nk;
                    if (nk == NDET) break;
                    kw &= ~rowb;
                }
            }
            if (lane == 0) s_K = nk;
        }
        __syncthreads();
        K = s_K;

        // ---- phase 5a: wave-local compactions (no block barriers inside) ----
        if (K < NDET) {
            if (wv == 0) {
                // suppressed positions, ascending sorted position
                int b = 0;
                for (int start = 0; start < V && b < NDET; start += 64) {
                    int p = start + lane;
                    unsigned int kword = (unsigned int)__shfl((int)kw, (p >> 5) & 15);
                    bool f = (p < V) && !((kword >> (p & 31)) & 1u);
                    unsigned long long mb = __ballot(f);
                    int pos = b + __popcll(mb & ((1ull << lane) - 1ull));
                    if (f && pos < NDET) s_supOut[pos] = (unsigned short)p;
                    b += (int)__popcll(mb);
                }
            } else if (wv == 1) {
                // invalid proposals, ascending original index
                int b = 0;
                for (int start = 0; start < NPROP && b < NDET; start += 64) {
                    int n = start + lane;
                    bool f = (s_scu[n] < 0.0f);
                    unsigned long long mb = __ballot(f);
                    int pos = b + __popcll(mb & ((1ull << lane) - 1ull));
                    if (f && pos < NDET) s_invOut[pos] = (unsigned short)n;
                    b += (int)__popcll(mb);
                }
            }
        }
        __syncthreads();
    } else {
        // ---- fallback (V > VMAX): proven round-1 block-wide path ----
        for (int p = tid; p < V; p += NBLK) s_keep[p] = 1;
        __syncthreads();
        int nk = 0;
        for (int i = 0; i < V; ++i) {
            if (s_keep[i]) {
                if (tid == 0) s_keepOut[nk] = (unsigned short)i;
                nk++;
                if (nk == NDET) break;
                int ni = s_ord[i];
                float ax1 = s_x1u[ni], ay1 = s_y1u[ni], ax2 = s_x2u[ni], ay2 = s_y2u[ni];
                float areaA = (ax2 - ax1) * (ay2 - ay1);
                for (int j = i + 1 + tid; j < V; j += NBLK) {
                    if (!s_keep[j]) continue;
                    int nj = s_ord[j];
                    float bx1 = s_x1u[nj], by1 = s_y1u[nj], bx2 = s_x2u[nj], by2 = s_y2u[nj];
                    float areaB = (bx2 - bx1) * (by2 - by1);
                    float lx = fmaxf(ax1, bx1), ly = fmaxf(ay1, by1);
                    float rx = fminf(ax2, bx2), ry = fminf(ay2, by2);
                    float iw = fmaxf(rx - lx, 0.0f), ih = fmaxf(ry - ly, 0.0f);
                    float inter = iw * ih;
                    float iou = inter / (areaA + areaB - inter + 1e-9f);
                    if (iou > NMS_THRESH) s_keep[j] = 0;
                }
                __syncthreads();
            }
        }
        if (tid == 0) s_K = nk;
        __syncthreads();
        K = s_K;

        if (K < NDET) {
            int base = 0;
            for (int start = 0; start < V && base < NDET; start += NBLK) {
                int p = start + tid;
                bool f = (p < V) && (!s_keep[p]);
                unsigned long long mb = __ballot(f);
                if (lane == 0) s_wcnt[wv] = __popcll(mb);
                __syncthreads();
                int wbase = base;
                for (int ww = 0; ww < wv; ++ww) wbase += s_wcnt[ww];
                if (f) {
                    int pos = wbase + __popcll(mb & ((1ull << lane) - 1ull));
                    if (pos < NDET) s_supOut[pos] = (unsigned short)p;
                }
                base += s_wcnt[0] + s_wcnt[1] + s_wcnt[2] + s_wcnt[3];
                __syncthreads();
            }
            base = 0;
            for (int start = 0; start < NPROP && base < NDET; start += NBLK) {
                int n = start + tid;
                bool f = (n < NPROP) && (s_scu[n] < 0.0f);
                unsigned long long mb = __ballot(f);
                if (lane == 0) s_wcnt[wv] = __popcll(mb);
                __syncthreads();
                int wbase = base;
                for (int ww = 0; ww < wv; ++ww) wbase += s_wcnt[ww];
                if (f) {
                    int pos = wbase + __popcll(mb & ((1ull << lane) - 1ull));
                    if (pos < NDET) s_invOut[pos] = (unsigned short)n;
                }
                base += s_wcnt[0] + s_wcnt[1] + s_wcnt[2] + s_wcnt[3];
                __syncthreads();
            }
        }
        __syncthreads();
    }

    const int nsupT = (K < NDET) ? (V - K) : 0;

    // ---- output: boxes | scores | labels | valid (class-major) ----
    float* out_boxes  = out;
    float* out_scores = out + NFG * NDET * 4;
    float* out_labels = out + NFG * NDET * 4 + NFG * NDET;
    float* out_valid  = out + NFG * NDET * 4 + 2 * NFG * NDET;
    const int base_o = (c - 1) * NDET;

    for (int k = tid; k < NDET; k += NBLK) {
        int n; float sc, vf;
        if (k < K) {
            n = s_ord[s_keepOut[k]];
            sc = s_scu[n]; vf = 1.0f;
        } else {
            int j = k - K;
            n = (j < nsupT) ? s_ord[s_supOut[j]] : s_invOut[j - nsupT];
            sc = -1.0f; vf = 0.0f;
        }
        out_boxes[(base_o + k) * 4 + 0] = s_x1u[n];
        out_boxes[(base_o + k) * 4 + 1] = s_y1u[n];
        out_boxes[(base_o + k) * 4 + 2] = s_x2u[n];
        out_boxes[(base_o + k) * 4 + 3] = s_y2u[n];
        out_scores[base_o + k] = sc;
        out_labels[base_o + k] = (float)c;
        out_valid[base_o + k]  = vf;
    }
}

extern "C" void kernel_launch(void* const* d_in, const int* in_sizes, int n_in,
                              void* d_out, int out_size, void* d_ws, size_t ws_size,
                              hipStream_t stream) {
    const float* logits = (const float*)d_in[0];  // [2000, 81]
    const float* reg    = (const float*)d_in[1];  // [2000, 324]
    const float* prop   = (const float*)d_in[2];  // [2000, 4]
    float* out = (float*)d_out;

    perclass_kernel<<<NFG, NBLK, 0, stream>>>(logits, reg, prop, out);
}

// Round 4
// 104.102 us; speedup vs baseline: 2.0900x; 2.0900x over previous
//
#include <hip/hip_runtime.h>
#include <math.h>

#define NPROP 2000
#define NCLS  81
#define NFG   80
#define NDET  100
#define NBLK  512
#define VMAX  512
#define WMAX  16          // VMAX/32 words per suppression-matrix row

#define SBLK  256
#define SROWS 80          // rows per stats block; grid = 2000/80 = 25

#define IMGW 800.0f
#define IMGH 800.0f
#define SCORE_THRESH 0.05f
#define NMS_THRESH 0.5f
#define MIN_SIZE 1.0f
#define BBOX_CLIP 4.135166556742356f  // log(1000/16)

// ---------------- kernel 1: per-row softmax stats via LDS staging ----------------
// Coalesced global->LDS load, then one thread per row runs the SAME sequential
// fmaxf / expf-sum chain as before -> bitwise-identical scores.
__global__ __launch_bounds__(SBLK) void stats_kernel(const float* __restrict__ logits,
                                                     float* __restrict__ stats) {
    __shared__ float tile[SROWS * NCLS];   // 80*81*4 = 25.9 KB
    const int base = blockIdx.x * (SROWS * NCLS);
    for (int t = threadIdx.x; t < SROWS * NCLS; t += SBLK)
        tile[t] = logits[base + t];
    __syncthreads();
    const int r = threadIdx.x;
    if (r < SROWS) {
        const float* row = tile + r * NCLS;
        float m = -1e30f;
        for (int k = 0; k < NCLS; ++k) m = fmaxf(m, row[k]);
        float s = 0.0f;
        for (int k = 0; k < NCLS; ++k) s += expf(row[k] - m);
        const int n = blockIdx.x * SROWS + r;
        stats[2 * n]     = m;
        stats[2 * n + 1] = s;
    }
}

// ---------------- kernel 2: one block per foreground class ----------------
__global__ __launch_bounds__(NBLK) void perclass_kernel(
        const float* __restrict__ logits,  // [NPROP, NCLS]
        const float* __restrict__ stats,   // [NPROP, 2]
        const float* __restrict__ reg,     // [NPROP, NCLS*4]
        const float* __restrict__ prop,    // [NPROP, 4]
        float* __restrict__ out) {
    const int c    = blockIdx.x + 1;   // foreground class 1..80
    const int tid  = threadIdx.x;
    const int lane = tid & 63;
    const int wv   = tid >> 6;

    __shared__ float s_x1u[NPROP], s_y1u[NPROP], s_x2u[NPROP], s_y2u[NPROP];
    __shared__ float s_scu[NPROP];                 // score if valid else -1
    __shared__ float s_vsc[NPROP];                 // valid-list scores (unordered)
    __shared__ unsigned short s_vlist[NPROP];      // valid-list original indices
    __shared__ unsigned short s_ord[NPROP];        // rank -> original index
    __shared__ unsigned char  s_keep[NPROP];       // fallback path only
    __shared__ unsigned int   s_supm[VMAX * WMAX]; // suppression bit matrix
    __shared__ unsigned short s_keepOut[NDET], s_supOut[NDET], s_invOut[NDET];
    __shared__ int s_cnt, s_K, s_wcnt[8];

    if (tid == 0) s_cnt = 0;
    __syncthreads();

    // ---- phase 1: score from stats + decode + clip + validity ----
    for (int n = tid; n < NPROP; n += NBLK) {
        float  lg = logits[n * NCLS + c];
        float2 st = ((const float2*)stats)[n];
        float  sc = expf(lg - st.x) / st.y;

        float4 pr = ((const float4*)prop)[n];
        float w  = pr.z - pr.x, h = pr.w - pr.y;
        float cx = pr.x + 0.5f * w, cy = pr.y + 0.5f * h;
        float4 d = *(const float4*)(reg + (size_t)n * (NCLS * 4) + c * 4);
        float dx = d.x / 10.0f;
        float dy = d.y / 10.0f;
        float dw = fminf(d.z / 5.0f, BBOX_CLIP);
        float dh = fminf(d.w / 5.0f, BBOX_CLIP);
        float pcx = dx * w + cx;
        float pcy = dy * h + cy;
        float pw  = expf(dw) * w;
        float ph  = expf(dh) * h;
        float bx1 = fminf(fmaxf(pcx - 0.5f * pw, 0.0f), IMGW);
        float by1 = fminf(fmaxf(pcy - 0.5f * ph, 0.0f), IMGH);
        float bx2 = fminf(fmaxf(pcx + 0.5f * pw, 0.0f), IMGW);
        float by2 = fminf(fmaxf(pcy + 0.5f * ph, 0.0f), IMGH);
        s_x1u[n] = bx1; s_y1u[n] = by1; s_x2u[n] = bx2; s_y2u[n] = by2;
        bool valid = (sc >= SCORE_THRESH) && ((bx2 - bx1) >= MIN_SIZE)
                                          && ((by2 - by1) >= MIN_SIZE);
        s_scu[n] = valid ? sc : -1.0f;
        if (valid) {
            int p = atomicAdd(&s_cnt, 1);
            s_vlist[p] = (unsigned short)n;
            s_vsc[p]   = sc;
        }
    }
    __syncthreads();
    const int V = s_cnt;

    // ---- phase 2: rank sort (score desc, index asc) ----
    for (int i = tid; i < V; i += NBLK) {
        float si = s_vsc[i];
        int   ni = s_vlist[i];
        int r = 0;
        for (int j = 0; j < V; ++j) {
            float sj = s_vsc[j];
            int   nj = s_vlist[j];
            r += (sj > si) || (sj == si && nj < ni);
        }
        s_ord[r] = (unsigned short)ni;
    }
    __syncthreads();

    int K;

    if (V <= VMAX) {
        // ---- phase 3a: build suppression bit matrix in parallel ----
        const int W = (V + 31) >> 5;
        for (int t = tid; t < V * W; t += NBLK) {
            int i = t / W, w = t - i * W;
            int ni = s_ord[i];
            float ax1 = s_x1u[ni], ay1 = s_y1u[ni], ax2 = s_x2u[ni], ay2 = s_y2u[ni];
            float areaA = (ax2 - ax1) * (ay2 - ay1);
            unsigned int bits = 0;
            int jbase = w << 5;
            int jend  = (jbase + 32 < V) ? jbase + 32 : V;
            int j0    = (jbase > i + 1) ? jbase : i + 1;
            for (int j = j0; j < jend; ++j) {
                int nj = s_ord[j];
                float bx1 = s_x1u[nj], by1 = s_y1u[nj], bx2 = s_x2u[nj], by2 = s_y2u[nj];
                float areaB = (bx2 - bx1) * (by2 - by1);
                float lx = fmaxf(ax1, bx1), ly = fmaxf(ay1, by1);
                float rx = fminf(ax2, bx2), ry = fminf(ay2, by2);
                float iw = fmaxf(rx - lx, 0.0f), ih = fmaxf(ry - ly, 0.0f);
                float inter = iw * ih;
                float iou = inter / (areaA + areaB - inter + 1e-9f);
                if (iou > NMS_THRESH) bits |= 1u << (j - jbase);
            }
            s_supm[i * W + w] = bits;
        }
        __syncthreads();

        // ---- phase 4a: serial greedy scan, single wave, register keep-mask ----
        unsigned int kw = 0;                    // lane l owns keep word l
        if (wv == 0) {
            int base = lane << 5;
            if (base < V) kw = (V - base >= 32) ? 0xffffffffu
                                                : ((1u << (V - base)) - 1u);
            int nk = 0;
            unsigned int nrow = (V > 0 && lane < W) ? s_supm[lane] : 0u;
            for (int i = 0; i < V; ++i) {
                unsigned int rowb = nrow;
                if (i + 1 < V) nrow = (lane < W) ? s_supm[(i + 1) * W + lane] : 0u;
                unsigned int kword = (unsigned int)__shfl((int)kw, i >> 5);
                if ((kword >> (i & 31)) & 1u) {
                    if (lane == 0) s_keepOut[nk] = (unsigned short)i;
                    ++nk;
                    if (nk == NDET) break;
                    kw &= ~rowb;
                }
            }
            if (lane == 0) s_K = nk;
        }
        __syncthreads();
        K = s_K;

        // ---- phase 5a: wave-local compactions (no block barriers inside) ----
        if (K < NDET) {
            if (wv == 0) {
                // suppressed positions, ascending sorted position
                int b = 0;
                for (int start = 0; start < V && b < NDET; start += 64) {
                    int p = start + lane;
                    unsigned int kword = (unsigned int)__shfl((int)kw, (p >> 5) & 15);
                    bool f = (p < V) && !((kword >> (p & 31)) & 1u);
                    unsigned long long mb = __ballot(f);
                    int pos = b + __popcll(mb & ((1ull << lane) - 1ull));
                    if (f && pos < NDET) s_supOut[pos] = (unsigned short)p;
                    b += (int)__popcll(mb);
                }
            } else if (wv == 1) {
                // invalid proposals, ascending original index
                int b = 0;
                for (int start = 0; start < NPROP && b < NDET; start += 64) {
                    int n = start + lane;
                    bool f = (s_scu[n] < 0.0f);
                    unsigned long long mb = __ballot(f);
                    int pos = b + __popcll(mb & ((1ull << lane) - 1ull));
                    if (f && pos < NDET) s_invOut[pos] = (unsigned short)n;
                    b += (int)__popcll(mb);
                }
            }
        }
        __syncthreads();
    } else {
        // ---- fallback (V > VMAX): block-wide greedy NMS ----
        for (int p = tid; p < V; p += NBLK) s_keep[p] = 1;
        __syncthreads();
        int nk = 0;
        for (int i = 0; i < V; ++i) {
            if (s_keep[i]) {
                if (tid == 0) s_keepOut[nk] = (unsigned short)i;
                nk++;
                if (nk == NDET) break;
                int ni = s_ord[i];
                float ax1 = s_x1u[ni], ay1 = s_y1u[ni], ax2 = s_x2u[ni], ay2 = s_y2u[ni];
                float areaA = (ax2 - ax1) * (ay2 - ay1);
                for (int j = i + 1 + tid; j < V; j += NBLK) {
                    if (!s_keep[j]) continue;
                    int nj = s_ord[j];
                    float bx1 = s_x1u[nj], by1 = s_y1u[nj], bx2 = s_x2u[nj], by2 = s_y2u[nj];
                    float areaB = (bx2 - bx1) * (by2 - by1);
                    float lx = fmaxf(ax1, bx1), ly = fmaxf(ay1, by1);
                    float rx = fminf(ax2, bx2), ry = fminf(ay2, by2);
                    float iw = fmaxf(rx - lx, 0.0f), ih = fmaxf(ry - ly, 0.0f);
                    float inter = iw * ih;
                    float iou = inter / (areaA + areaB - inter + 1e-9f);
                    if (iou > NMS_THRESH) s_keep[j] = 0;
                }
                __syncthreads();
            }
        }
        if (tid == 0) s_K = nk;
        __syncthreads();
        K = s_K;

        if (K < NDET) {
            int base = 0;
            for (int start = 0; start < V && base < NDET; start += NBLK) {
                int p = start + tid;
                bool f = (p < V) && (!s_keep[p]);
                unsigned long long mb = __ballot(f);
                if (lane == 0) s_wcnt[wv] = __popcll(mb);
                __syncthreads();
                int wbase = base;
                for (int ww = 0; ww < wv; ++ww) wbase += s_wcnt[ww];
                if (f) {
                    int pos = wbase + __popcll(mb & ((1ull << lane) - 1ull));
                    if (pos < NDET) s_supOut[pos] = (unsigned short)p;
                }
                for (int ww = 0; ww < 8; ++ww) base += s_wcnt[ww];
                __syncthreads();
            }
            base = 0;
            for (int start = 0; start < NPROP && base < NDET; start += NBLK) {
                int n = start + tid;
                bool f = (n < NPROP) && (s_scu[n] < 0.0f);
                unsigned long long mb = __ballot(f);
                if (lane == 0) s_wcnt[wv] = __popcll(mb);
                __syncthreads();
                int wbase = base;
                for (int ww = 0; ww < wv; ++ww) wbase += s_wcnt[ww];
                if (f) {
                    int pos = wbase + __popcll(mb & ((1ull << lane) - 1ull));
                    if (pos < NDET) s_invOut[pos] = (unsigned short)n;
                }
                for (int ww = 0; ww < 8; ++ww) base += s_wcnt[ww];
                __syncthreads();
            }
        }
        __syncthreads();
    }

    const int nsupT = (K < NDET) ? (V - K) : 0;

    // ---- output: boxes | scores | labels | valid (class-major) ----
    float* out_boxes  = out;
    float* out_scores = out + NFG * NDET * 4;
    float* out_labels = out + NFG * NDET * 4 + NFG * NDET;
    float* out_valid  = out + NFG * NDET * 4 + 2 * NFG * NDET;
    const int base_o = (c - 1) * NDET;

    for (int k = tid; k < NDET; k += NBLK) {
        int n; float sc, vf;
        if (k < K) {
            n = s_ord[s_keepOut[k]];
            sc = s_scu[n]; vf = 1.0f;
        } else {
            int j = k - K;
            n = (j < nsupT) ? s_ord[s_supOut[j]] : s_invOut[j - nsupT];
            sc = -1.0f; vf = 0.0f;
        }
        out_boxes[(base_o + k) * 4 + 0] = s_x1u[n];
        out_boxes[(base_o + k) * 4 + 1] = s_y1u[n];
        out_boxes[(base_o + k) * 4 + 2] = s_x2u[n];
        out_boxes[(base_o + k) * 4 + 3] = s_y2u[n];
        out_scores[base_o + k] = sc;
        out_labels[base_o + k] = (float)c;
        out_valid[base_o + k]  = vf;
    }
}

extern "C" void kernel_launch(void* const* d_in, const int* in_sizes, int n_in,
                              void* d_out, int out_size, void* d_ws, size_t ws_size,
                              hipStream_t stream) {
    const float* logits = (const float*)d_in[0];  // [2000, 81]
    const float* reg    = (const float*)d_in[1];  // [2000, 324]
    const float* prop   = (const float*)d_in[2];  // [2000, 4]
    float* out   = (float*)d_out;
    float* stats = (float*)d_ws;                  // [2000, 2] floats

    stats_kernel<<<NPROP / SROWS, SBLK, 0, stream>>>(logits, stats);
    perclass_kernel<<<NFG, NBLK, 0, stream>>>(logits, stats, reg, prop, out);
}